// Round 7
// baseline (51.175 us; speedup 1.0000x reference)
//
#include <hip/hip_runtime.h>
#include <hip/hip_bf16.h>
#include <cstdint>
#include <cstddef>

#define NB 2048
#define TAU 32
#define T0C 96
#define LQ 128      // T0 + tau
#define DD 64
#define DOUT 64
#define KK 16

typedef unsigned long long u64;
typedef __attribute__((ext_vector_type(8))) short short8;
typedef __attribute__((ext_vector_type(4))) float f32x4;

#define KINV 1e30   // invalid-key sentinel (valid keys < 2^38)

// exact-rounding helpers: keep d2 bit-identical to the reference (no fma fusion)
__device__ __forceinline__ float fmul_exact(float a, float b) {
  float r; asm("v_mul_f32 %0, %1, %2" : "=v"(r) : "v"(a), "v"(b)); return r;
}
__device__ __forceinline__ float fadd_exact(float a, float b) {
  float r; asm("v_add_f32 %0, %1, %2" : "=v"(r) : "v"(a), "v"(b)); return r;
}
__device__ __forceinline__ unsigned short f2bf(float f) {
  __hip_bfloat16 h = __float2bfloat16(f);
  return *reinterpret_cast<unsigned short*>(&h);
}
__device__ __forceinline__ double shfl_xor_f64(double v, int mask) {
  u64 u = __double_as_longlong(v);
  int lo = __shfl_xor((int)(unsigned)(u & 0xffffffffULL), mask, 64);
  int hi = __shfl_xor((int)(unsigned)(u >> 32), mask, 64);
  return __longlong_as_double(((u64)(unsigned)hi << 32) | (unsigned)lo);
}

// compare-exchange: ascending (min to first) / descending (max to first)
#define CA(i, j) { double _lo = fmin(kd[i], kd[j]); double _hi = fmax(kd[i], kd[j]); kd[i] = _lo; kd[j] = _hi; }
#define CD(i, j) { double _lo = fmin(kd[i], kd[j]); double _hi = fmax(kd[i], kd[j]); kd[i] = _hi; kd[j] = _lo; }

// full bitonic sort of kd[0..15], ascending (static network, 80 CAS)
#define SORT16() do { \
  CA(0,1)  CD(2,3)  CA(4,5)  CD(6,7)  CA(8,9)  CD(10,11) CA(12,13) CD(14,15) \
  CA(0,2)  CA(1,3)  CD(4,6)  CD(5,7)  CA(8,10) CA(9,11)  CD(12,14) CD(13,15) \
  CA(0,1)  CA(2,3)  CD(4,5)  CD(6,7)  CA(8,9)  CA(10,11) CD(12,13) CD(14,15) \
  CA(0,4)  CA(1,5)  CA(2,6)  CA(3,7)  CD(8,12) CD(9,13)  CD(10,14) CD(11,15) \
  CA(0,2)  CA(1,3)  CA(4,6)  CA(5,7)  CD(8,10) CD(9,11)  CD(12,14) CD(13,15) \
  CA(0,1)  CA(2,3)  CA(4,5)  CA(6,7)  CD(8,9)  CD(10,11) CD(12,13) CD(14,15) \
  CA(0,8)  CA(1,9)  CA(2,10) CA(3,11) CA(4,12) CA(5,13)  CA(6,14)  CA(7,15)  \
  CA(0,4)  CA(1,5)  CA(2,6)  CA(3,7)  CA(8,12) CA(9,13)  CA(10,14) CA(11,15) \
  CA(0,2)  CA(1,3)  CA(4,6)  CA(5,7)  CA(8,10) CA(9,11)  CA(12,14) CA(13,15) \
  CA(0,1)  CA(2,3)  CA(4,5)  CA(6,7)  CA(8,9)  CA(10,11) CA(12,13) CA(14,15) \
} while (0)

// bitonic merge of a bitonic kd[0..15] -> ascending (4 stages, 32 CAS)
#define MERGE16() do { \
  CA(0,8)  CA(1,9)  CA(2,10) CA(3,11) CA(4,12) CA(5,13)  CA(6,14)  CA(7,15)  \
  CA(0,4)  CA(1,5)  CA(2,6)  CA(3,7)  CA(8,12) CA(9,13)  CA(10,14) CA(11,15) \
  CA(0,2)  CA(1,3)  CA(4,6)  CA(5,7)  CA(8,10) CA(9,11)  CA(12,14) CA(13,15) \
  CA(0,1)  CA(2,3)  CA(4,5)  CA(6,7)  CA(8,9)  CA(10,11) CA(12,13) CA(14,15) \
} while (0)

// merge sorted kd with partner lane's sorted list (xor mask), keep lowest 16
#define SHUF_MERGE(mask) do { \
  double pb[16]; \
  _Pragma("unroll") \
  for (int _i = 0; _i < 16; ++_i) pb[_i] = shfl_xor_f64(kd[15 - _i], mask); \
  _Pragma("unroll") \
  for (int _i = 0; _i < 16; ++_i) kd[_i] = fmin(kd[_i], pb[_i]); \
  MERGE16(); \
} while (0)

// ---------- pre-kernel: bf16 transposed weights into d_ws ----------
// wst[0..4095]      = Wn_t[n][k]  = bf16(W_nbr[k][n])
// wst[4096..8191]   = Wsf_t[n][k] = bf16(W_self[k][n])
__global__ __launch_bounds__(256) void prep_w(
    const float* __restrict__ W_nbr, const float* __restrict__ W_self,
    unsigned short* __restrict__ wst) {
  int idx = blockIdx.x * 256 + threadIdx.x;   // grid 32 -> 8192
  int m = idx & 4095;
  int n = m >> 6, k = m & 63;
  const float* src = (idx < 4096) ? W_nbr : W_self;
  wst[idx] = f2bf(src[k * DOUT + n]);
}

__global__ __launch_bounds__(256, 6) void navgcm_fused(
    const float* __restrict__ x, const float* __restrict__ pos_in, const float* __restrict__ rot_in,
    const float* __restrict__ old_x, const float* __restrict__ old_pos, const float* __restrict__ old_rot,
    const float* __restrict__ W_self, const float* __restrict__ W_nbr, const float* __restrict__ bias,
    const unsigned short* __restrict__ wst,
    float* __restrict__ outp)
{
  const int b = blockIdx.x;
  const int tid = threadIdx.x;
  const int lane = tid & 63;
  const int wv = tid >> 6;
  const int fr = lane & 15;   // MFMA fragment row/col within tile
  const int fg = lane >> 4;   // MFMA fragment k-group / row-group

  // union: Hs[128][72] ushort (18432 B, phases A-C) <-> msgs bf16 [128][68] (17408 B, D-E)
  __shared__ __align__(16) unsigned char uni[18432];
  __shared__ float px[LQ], py[LQ], pz[LQ], rt[LQ];
  __shared__ uint4 selidx[32];

  unsigned short (*Hs)[72] = reinterpret_cast<unsigned short(*)[72]>(uni);
  unsigned short (*msgs)[68] = reinterpret_cast<unsigned short(*)[68]>(uni);

  // ================= phase A: copy + stage =================
  float4* dnx = (float4*)(outp + (size_t)NB * TAU * DOUT);
  #pragma unroll
  for (int it = 0; it < 8; ++it) {
    int n = tid + 256 * it;              // [0,2048): row = n>>4, c4 = n&15
    int row = n >> 4, c4 = n & 15;
    const float4* src = (row < T0C)
        ? (const float4*)(old_x + ((size_t)b * LQ + row) * DD)
        : (const float4*)(x + ((size_t)b * TAU + (row - T0C)) * DD);
    float4 v = src[c4];
    dnx[(size_t)b * 2048 + n] = v;       // new_x
    ushort4 w4;
    w4.x = f2bf(v.x); w4.y = f2bf(v.y); w4.z = f2bf(v.z); w4.w = f2bf(v.w);
    *reinterpret_cast<ushort4*>(&Hs[row][c4 * 4]) = w4;
  }

  float* dpos = outp + (size_t)NB * TAU * DOUT + (size_t)NB * LQ * DD;
  float* drot = dpos + (size_t)NB * LQ * 3;
  if (tid < LQ) {
    int t = tid;
    float p0, p1, p2, rr;
    if (t < T0C) {
      const float* s = old_pos + ((size_t)b * LQ + t) * 3;
      p0 = s[0]; p1 = s[1]; p2 = s[2];
      rr = old_rot[(size_t)b * LQ + t];
    } else {
      const float* s = pos_in + ((size_t)b * TAU + (t - T0C)) * 3;
      p0 = s[0]; p1 = s[1]; p2 = s[2];
      rr = rot_in[(size_t)b * TAU + (t - T0C)];
    }
    px[t] = p0; py[t] = p1; pz[t] = p2; rt[t] = rr;
    size_t g = (size_t)b * LQ + t;
    dpos[g * 3 + 0] = p0; dpos[g * 3 + 1] = p1; dpos[g * 3 + 2] = p2;
    drot[g] = rr;
  }
  __syncthreads();   // b1: Hs/pos ready

  // ========== phase B: selection, fully in registers + shuffles ==========
  {
    const int q = tid >> 3, s8 = tid & 7;
    const int i = T0C + q;
    const float pix = px[i], piy = py[i], piz = pz[i];
    double kd[16];
    #pragma unroll
    for (int c = 0; c < 16; ++c) {
      int j = 8 * c + s8;
      float dx = pix - px[j], dy = piy - py[j], dz = piz - pz[j];
      float d2 = fadd_exact(fadd_exact(fmul_exact(dx, dx), fmul_exact(dy, dy)),
                            fmul_exact(dz, dz));
      bool valid = (d2 <= 1.0f) && (j < i);
      double key = fma((double)__float_as_uint(d2), 128.0, (double)j);
      kd[c] = valid ? key : KINV;
    }
    SORT16();          // ascending per-thread sublist
    SHUF_MERGE(1);     // 8 -> 4 lists
    SHUF_MERGE(2);     // 4 -> 2
    SHUF_MERGE(4);     // 2 -> 1

    if (s8 == 0) {
      uint32_t w[4] = {0u, 0u, 0u, 0u};
      #pragma unroll
      for (int t = 0; t < KK; ++t) {
        double kv = kd[t];
        uint32_t jj;
        if (kv >= 1e29) {
          jj = 127u;                         // sentinel -> zero msg row
        } else {
          uint32_t d2b = (uint32_t)(kv * 0.0078125);       // trunc(kv/128)
          double rem = kv - 128.0 * (double)d2b;           // exact
          jj = (uint32_t)rem;
        }
        w[t >> 2] |= jj << ((t & 3) * 8);
      }
      uint4 sv; sv.x = w[0]; sv.y = w[1]; sv.z = w[2]; sv.w = w[3];
      selidx[q] = sv;
    }
  }

  // ================= phase C: MFMA (B-frags direct from d_ws) =================
  const unsigned short* wn_t = wst;            // [64][64] bf16, [n][k]
  const unsigned short* ws_t = wst + 4096;

  short8 bW[4][2];
  #pragma unroll
  for (int nt = 0; nt < 4; ++nt)
    #pragma unroll
    for (int ks = 0; ks < 2; ++ks)
      bW[nt][ks] = *reinterpret_cast<const short8*>(&wn_t[(nt * 16 + fr) * 64 + ks * 32 + fg * 8]);

  f32x4 acc[2][4];
  #pragma unroll
  for (int m = 0; m < 2; ++m)
    #pragma unroll
    for (int n = 0; n < 4; ++n)
      acc[m][n] = (f32x4){0.f, 0.f, 0.f, 0.f};

  #pragma unroll
  for (int mtl = 0; mtl < 2; ++mtl) {
    int mrow = (2 * wv + mtl) * 16;
    short8 a0 = *reinterpret_cast<const short8*>(&Hs[mrow + fr][fg * 8]);
    short8 a1 = *reinterpret_cast<const short8*>(&Hs[mrow + fr][32 + fg * 8]);
    #pragma unroll
    for (int nt = 0; nt < 4; ++nt) {
      acc[mtl][nt] = __builtin_amdgcn_mfma_f32_16x16x32_bf16(a0, bW[nt][0], acc[mtl][nt], 0, 0, 0);
      acc[mtl][nt] = __builtin_amdgcn_mfma_f32_16x16x32_bf16(a1, bW[nt][1], acc[mtl][nt], 0, 0, 0);
    }
  }

  // self-term MFMA (registers only)
  const int mt = wv & 1;
  const int ntb = (wv >> 1) * 2;
  short8 aQ0 = *reinterpret_cast<const short8*>(&Hs[T0C + mt * 16 + fr][fg * 8]);
  short8 aQ1 = *reinterpret_cast<const short8*>(&Hs[T0C + mt * 16 + fr][32 + fg * 8]);
  f32x4 acc2[2];
  #pragma unroll
  for (int n = 0; n < 2; ++n) acc2[n] = (f32x4){0.f, 0.f, 0.f, 0.f};
  #pragma unroll
  for (int ntl = 0; ntl < 2; ++ntl) {
    int nt = ntb + ntl;
    short8 b0 = *reinterpret_cast<const short8*>(&ws_t[(nt * 16 + fr) * 64 + fg * 8]);
    short8 b1 = *reinterpret_cast<const short8*>(&ws_t[(nt * 16 + fr) * 64 + 32 + fg * 8]);
    acc2[ntl] = __builtin_amdgcn_mfma_f32_16x16x32_bf16(aQ0, b0, acc2[ntl], 0, 0, 0);
    acc2[ntl] = __builtin_amdgcn_mfma_f32_16x16x32_bf16(aQ1, b1, acc2[ntl], 0, 0, 0);
  }
  __syncthreads();   // b2: all Hs reads done -> union reusable as msgs

  // ================= phase D: msgs = bf16(acc + pos-terms) -> LDS =================
  float wn4[4][4];
  #pragma unroll
  for (int nt = 0; nt < 4; ++nt) {
    int col = nt * 16 + fr;
    wn4[nt][0] = W_nbr[64 * DOUT + col];
    wn4[nt][1] = W_nbr[65 * DOUT + col];
    wn4[nt][2] = W_nbr[66 * DOUT + col];
    wn4[nt][3] = W_nbr[67 * DOUT + col];
  }
  #pragma unroll
  for (int mtl = 0; mtl < 2; ++mtl) {
    #pragma unroll
    for (int r = 0; r < 4; ++r) {
      int row = (2 * wv + mtl) * 16 + fg * 4 + r;   // C/D: row=(lane>>4)*4+reg
      float p0 = px[row], p1 = py[row], p2 = pz[row], p3 = rt[row];
      #pragma unroll
      for (int nt = 0; nt < 4; ++nt) {
        float v = acc[mtl][nt][r]
                + p0 * wn4[nt][0] + p1 * wn4[nt][1] + p2 * wn4[nt][2] + p3 * wn4[nt][3];
        msgs[row][nt * 16 + fr] = (row == LQ - 1) ? (unsigned short)0 : f2bf(v);
      }
    }
  }
  __syncthreads();   // b3: msgs + selidx ready

  // ================= phase E: gather + epilogue =================
  #pragma unroll
  for (int ntl = 0; ntl < 2; ++ntl) {
    int col = (ntb + ntl) * 16 + fr;
    float ws0 = W_self[64 * DOUT + col], ws1 = W_self[65 * DOUT + col];
    float ws2 = W_self[66 * DOUT + col], ws3 = W_self[67 * DOUT + col];
    float bi = bias[col];
    #pragma unroll
    for (int r = 0; r < 4; ++r) {
      int q = mt * 16 + fg * 4 + r;
      int row = T0C + q;
      uint4 sv = selidx[q];
      float agg = 0.f;
      #pragma unroll
      for (int s = 0; s < KK; ++s) {
        uint32_t wd = (s < 4) ? sv.x : (s < 8) ? sv.y : (s < 12) ? sv.z : sv.w;
        int j = (wd >> ((s & 3) * 8)) & 0xff;
        unsigned short mv = msgs[j][col];
        agg += __uint_as_float((uint32_t)mv << 16);
      }
      float v = acc2[ntl][r] + agg + bi
              + px[row] * ws0 + py[row] * ws1 + pz[row] * ws2 + rt[row] * ws3;
      v = fmaxf(v, 0.f);
      outp[((size_t)b * TAU + q) * DOUT + col] = v;
    }
  }
}

extern "C" void kernel_launch(void* const* d_in, const int* in_sizes, int n_in,
                              void* d_out, int out_size, void* d_ws, size_t ws_size,
                              hipStream_t stream) {
  (void)in_sizes; (void)n_in; (void)ws_size; (void)out_size;
  const float* x       = (const float*)d_in[0];
  const float* pos     = (const float*)d_in[1];
  const float* rot     = (const float*)d_in[2];
  const float* old_x   = (const float*)d_in[3];
  const float* old_pos = (const float*)d_in[4];
  const float* old_rot = (const float*)d_in[5];
  const float* W_self  = (const float*)d_in[6];
  const float* W_nbr   = (const float*)d_in[7];
  const float* bias    = (const float*)d_in[8];
  float* out = (float*)d_out;
  unsigned short* wst = (unsigned short*)d_ws;

  hipLaunchKernelGGL(prep_w, dim3(32), dim3(256), 0, stream, W_nbr, W_self, wst);
  hipLaunchKernelGGL(navgcm_fused, dim3(NB), dim3(256), 0, stream,
                     x, pos, rot, old_x, old_pos, old_rot, W_self, W_nbr, bias, wst, out);
}

// Round 8
// 49.867 us; speedup vs baseline: 1.0262x; 1.0262x over previous
//
#include <hip/hip_runtime.h>
#include <hip/hip_bf16.h>
#include <cstdint>
#include <cstddef>

#define NB 2048
#define TAU 32
#define T0C 96
#define LQ 128      // T0 + tau
#define DD 64
#define DOUT 64
#define KK 16

typedef unsigned long long u64;
typedef __attribute__((ext_vector_type(8))) short short8;
typedef __attribute__((ext_vector_type(4))) float f32x4;

#define KINV 1e30   // invalid-key sentinel (valid keys < 2^38)

// exact-rounding helpers: keep d2 bit-identical to the reference (no fma fusion)
__device__ __forceinline__ float fmul_exact(float a, float b) {
  float r; asm("v_mul_f32 %0, %1, %2" : "=v"(r) : "v"(a), "v"(b)); return r;
}
__device__ __forceinline__ float fadd_exact(float a, float b) {
  float r; asm("v_add_f32 %0, %1, %2" : "=v"(r) : "v"(a), "v"(b)); return r;
}
__device__ __forceinline__ unsigned short f2bf(float f) {
  __hip_bfloat16 h = __float2bfloat16(f);
  return *reinterpret_cast<unsigned short*>(&h);
}
__device__ __forceinline__ double shfl_xor_f64(double v, int mask) {
  u64 u = __double_as_longlong(v);
  int lo = __shfl_xor((int)(unsigned)(u & 0xffffffffULL), mask, 64);
  int hi = __shfl_xor((int)(unsigned)(u >> 32), mask, 64);
  return __longlong_as_double(((u64)(unsigned)hi << 32) | (unsigned)lo);
}

// compare-exchange: ascending (min to first) / descending (max to first)
#define CA(i, j) { double _lo = fmin(kd[i], kd[j]); double _hi = fmax(kd[i], kd[j]); kd[i] = _lo; kd[j] = _hi; }
#define CD(i, j) { double _lo = fmin(kd[i], kd[j]); double _hi = fmax(kd[i], kd[j]); kd[i] = _hi; kd[j] = _lo; }

// full bitonic sort of kd[0..15], ascending (static network, 80 CAS)
#define SORT16() do { \
  CA(0,1)  CD(2,3)  CA(4,5)  CD(6,7)  CA(8,9)  CD(10,11) CA(12,13) CD(14,15) \
  CA(0,2)  CA(1,3)  CD(4,6)  CD(5,7)  CA(8,10) CA(9,11)  CD(12,14) CD(13,15) \
  CA(0,1)  CA(2,3)  CD(4,5)  CD(6,7)  CA(8,9)  CA(10,11) CD(12,13) CD(14,15) \
  CA(0,4)  CA(1,5)  CA(2,6)  CA(3,7)  CD(8,12) CD(9,13)  CD(10,14) CD(11,15) \
  CA(0,2)  CA(1,3)  CA(4,6)  CA(5,7)  CD(8,10) CD(9,11)  CD(12,14) CD(13,15) \
  CA(0,1)  CA(2,3)  CA(4,5)  CA(6,7)  CD(8,9)  CD(10,11) CD(12,13) CD(14,15) \
  CA(0,8)  CA(1,9)  CA(2,10) CA(3,11) CA(4,12) CA(5,13)  CA(6,14)  CA(7,15)  \
  CA(0,4)  CA(1,5)  CA(2,6)  CA(3,7)  CA(8,12) CA(9,13)  CA(10,14) CA(11,15) \
  CA(0,2)  CA(1,3)  CA(4,6)  CA(5,7)  CA(8,10) CA(9,11)  CA(12,14) CA(13,15) \
  CA(0,1)  CA(2,3)  CA(4,5)  CA(6,7)  CA(8,9)  CA(10,11) CA(12,13) CA(14,15) \
} while (0)

// bitonic merge of a bitonic kd[0..15] -> ascending (4 stages, 32 CAS)
#define MERGE16() do { \
  CA(0,8)  CA(1,9)  CA(2,10) CA(3,11) CA(4,12) CA(5,13)  CA(6,14)  CA(7,15)  \
  CA(0,4)  CA(1,5)  CA(2,6)  CA(3,7)  CA(8,12) CA(9,13)  CA(10,14) CA(11,15) \
  CA(0,2)  CA(1,3)  CA(4,6)  CA(5,7)  CA(8,10) CA(9,11)  CA(12,14) CA(13,15) \
  CA(0,1)  CA(2,3)  CA(4,5)  CA(6,7)  CA(8,9)  CA(10,11) CA(12,13) CA(14,15) \
} while (0)

// merge sorted kd with partner lane's sorted list (xor mask), keep lowest 16
#define SHUF_MERGE(mask) do { \
  double pb[16]; \
  _Pragma("unroll") \
  for (int _i = 0; _i < 16; ++_i) pb[_i] = shfl_xor_f64(kd[15 - _i], mask); \
  _Pragma("unroll") \
  for (int _i = 0; _i < 16; ++_i) kd[_i] = fmin(kd[_i], pb[_i]); \
  MERGE16(); \
} while (0)

// ---------- pre-kernel: bf16 transposed weights into d_ws ----------
// wst[0..4095]      = Wn_t[n][k]  = bf16(W_nbr[k][n])
// wst[4096..8191]   = Wsf_t[n][k] = bf16(W_self[k][n])
__global__ __launch_bounds__(256) void prep_w(
    const float* __restrict__ W_nbr, const float* __restrict__ W_self,
    unsigned short* __restrict__ wst) {
  int idx = blockIdx.x * 256 + threadIdx.x;   // grid 32 -> 8192
  int m = idx & 4095;
  int n = m >> 6, k = m & 63;
  const float* src = (idx < 4096) ? W_nbr : W_self;
  wst[idx] = f2bf(src[k * DOUT + n]);
}

__global__ __launch_bounds__(256, 4) void navgcm_fused(
    const float* __restrict__ x, const float* __restrict__ pos_in, const float* __restrict__ rot_in,
    const float* __restrict__ old_x, const float* __restrict__ old_pos, const float* __restrict__ old_rot,
    const float* __restrict__ W_self, const float* __restrict__ W_nbr, const float* __restrict__ bias,
    const unsigned short* __restrict__ wst,
    float* __restrict__ outp)
{
  const int b = blockIdx.x;
  const int tid = threadIdx.x;
  const int lane = tid & 63;
  const int wv = tid >> 6;
  const int fr = lane & 15;   // MFMA fragment row/col within tile
  const int fg = lane >> 4;   // MFMA fragment k-group / row-group

  // union: Hs[128][72] ushort (18432 B, phases A-C) <-> msgs bf16 [128][68] (17408 B, D-E)
  __shared__ __align__(16) unsigned char uni[18432];
  __shared__ float px[LQ], py[LQ], pz[LQ], rt[LQ];
  __shared__ uint4 selidx[32];

  unsigned short (*Hs)[72] = reinterpret_cast<unsigned short(*)[72]>(uni);
  unsigned short (*msgs)[68] = reinterpret_cast<unsigned short(*)[68]>(uni);

  // ================= phase A: copy + stage =================
  float4* dnx = (float4*)(outp + (size_t)NB * TAU * DOUT);
  #pragma unroll
  for (int it = 0; it < 8; ++it) {
    int n = tid + 256 * it;              // [0,2048): row = n>>4, c4 = n&15
    int row = n >> 4, c4 = n & 15;
    const float4* src = (row < T0C)
        ? (const float4*)(old_x + ((size_t)b * LQ + row) * DD)
        : (const float4*)(x + ((size_t)b * TAU + (row - T0C)) * DD);
    float4 v = src[c4];
    dnx[(size_t)b * 2048 + n] = v;       // new_x
    ushort4 w4;
    w4.x = f2bf(v.x); w4.y = f2bf(v.y); w4.z = f2bf(v.z); w4.w = f2bf(v.w);
    *reinterpret_cast<ushort4*>(&Hs[row][c4 * 4]) = w4;
  }

  float* dpos = outp + (size_t)NB * TAU * DOUT + (size_t)NB * LQ * DD;
  float* drot = dpos + (size_t)NB * LQ * 3;
  if (tid < LQ) {
    int t = tid;
    float p0, p1, p2, rr;
    if (t < T0C) {
      const float* s = old_pos + ((size_t)b * LQ + t) * 3;
      p0 = s[0]; p1 = s[1]; p2 = s[2];
      rr = old_rot[(size_t)b * LQ + t];
    } else {
      const float* s = pos_in + ((size_t)b * TAU + (t - T0C)) * 3;
      p0 = s[0]; p1 = s[1]; p2 = s[2];
      rr = rot_in[(size_t)b * TAU + (t - T0C)];
    }
    px[t] = p0; py[t] = p1; pz[t] = p2; rt[t] = rr;
    size_t g = (size_t)b * LQ + t;
    dpos[g * 3 + 0] = p0; dpos[g * 3 + 1] = p1; dpos[g * 3 + 2] = p2;
    drot[g] = rr;
  }
  __syncthreads();   // b1: Hs/pos ready

  // ========== phase B: selection, fully in registers + shuffles ==========
  {
    const int q = tid >> 3, s8 = tid & 7;
    const int i = T0C + q;
    const float pix = px[i], piy = py[i], piz = pz[i];
    double kd[16];
    #pragma unroll
    for (int c = 0; c < 16; ++c) {
      int j = 8 * c + s8;
      float dx = pix - px[j], dy = piy - py[j], dz = piz - pz[j];
      float d2 = fadd_exact(fadd_exact(fmul_exact(dx, dx), fmul_exact(dy, dy)),
                            fmul_exact(dz, dz));
      bool valid = (d2 <= 1.0f) && (j < i);
      double key = fma((double)__float_as_uint(d2), 128.0, (double)j);
      kd[c] = valid ? key : KINV;
    }
    SORT16();          // ascending per-thread sublist
    SHUF_MERGE(1);     // 8 -> 4 lists
    SHUF_MERGE(2);     // 4 -> 2
    SHUF_MERGE(4);     // 2 -> 1

    if (s8 == 0) {
      uint32_t w[4] = {0u, 0u, 0u, 0u};
      #pragma unroll
      for (int t = 0; t < KK; ++t) {
        double kv = kd[t];
        uint32_t jj;
        if (kv >= 1e29) {
          jj = 127u;                         // sentinel -> zero msg row
        } else {
          uint32_t d2b = (uint32_t)(kv * 0.0078125);       // trunc(kv/128)
          double rem = kv - 128.0 * (double)d2b;           // exact
          jj = (uint32_t)rem;
        }
        w[t >> 2] |= jj << ((t & 3) * 8);
      }
      uint4 sv; sv.x = w[0]; sv.y = w[1]; sv.z = w[2]; sv.w = w[3];
      selidx[q] = sv;
    }
  }

  // ================= phase C: MFMA (B-frags direct from d_ws) =================
  const unsigned short* wn_t = wst;            // [64][64] bf16, [n][k]
  const unsigned short* ws_t = wst + 4096;

  short8 bW[4][2];
  #pragma unroll
  for (int nt = 0; nt < 4; ++nt)
    #pragma unroll
    for (int ks = 0; ks < 2; ++ks)
      bW[nt][ks] = *reinterpret_cast<const short8*>(&wn_t[(nt * 16 + fr) * 64 + ks * 32 + fg * 8]);

  f32x4 acc[2][4];
  #pragma unroll
  for (int m = 0; m < 2; ++m)
    #pragma unroll
    for (int n = 0; n < 4; ++n)
      acc[m][n] = (f32x4){0.f, 0.f, 0.f, 0.f};

  #pragma unroll
  for (int mtl = 0; mtl < 2; ++mtl) {
    int mrow = (2 * wv + mtl) * 16;
    short8 a0 = *reinterpret_cast<const short8*>(&Hs[mrow + fr][fg * 8]);
    short8 a1 = *reinterpret_cast<const short8*>(&Hs[mrow + fr][32 + fg * 8]);
    #pragma unroll
    for (int nt = 0; nt < 4; ++nt) {
      acc[mtl][nt] = __builtin_amdgcn_mfma_f32_16x16x32_bf16(a0, bW[nt][0], acc[mtl][nt], 0, 0, 0);
      acc[mtl][nt] = __builtin_amdgcn_mfma_f32_16x16x32_bf16(a1, bW[nt][1], acc[mtl][nt], 0, 0, 0);
    }
  }

  // self-term MFMA (registers only)
  const int mt = wv & 1;
  const int ntb = (wv >> 1) * 2;
  short8 aQ0 = *reinterpret_cast<const short8*>(&Hs[T0C + mt * 16 + fr][fg * 8]);
  short8 aQ1 = *reinterpret_cast<const short8*>(&Hs[T0C + mt * 16 + fr][32 + fg * 8]);
  f32x4 acc2[2];
  #pragma unroll
  for (int n = 0; n < 2; ++n) acc2[n] = (f32x4){0.f, 0.f, 0.f, 0.f};
  #pragma unroll
  for (int ntl = 0; ntl < 2; ++ntl) {
    int nt = ntb + ntl;
    short8 b0 = *reinterpret_cast<const short8*>(&ws_t[(nt * 16 + fr) * 64 + fg * 8]);
    short8 b1 = *reinterpret_cast<const short8*>(&ws_t[(nt * 16 + fr) * 64 + 32 + fg * 8]);
    acc2[ntl] = __builtin_amdgcn_mfma_f32_16x16x32_bf16(aQ0, b0, acc2[ntl], 0, 0, 0);
    acc2[ntl] = __builtin_amdgcn_mfma_f32_16x16x32_bf16(aQ1, b1, acc2[ntl], 0, 0, 0);
  }
  __syncthreads();   // b2: all Hs reads done -> union reusable as msgs

  // ================= phase D: msgs = bf16(acc + pos-terms) -> LDS =================
  float wn4[4][4];
  #pragma unroll
  for (int nt = 0; nt < 4; ++nt) {
    int col = nt * 16 + fr;
    wn4[nt][0] = W_nbr[64 * DOUT + col];
    wn4[nt][1] = W_nbr[65 * DOUT + col];
    wn4[nt][2] = W_nbr[66 * DOUT + col];
    wn4[nt][3] = W_nbr[67 * DOUT + col];
  }
  #pragma unroll
  for (int mtl = 0; mtl < 2; ++mtl) {
    #pragma unroll
    for (int r = 0; r < 4; ++r) {
      int row = (2 * wv + mtl) * 16 + fg * 4 + r;   // C/D: row=(lane>>4)*4+reg
      float p0 = px[row], p1 = py[row], p2 = pz[row], p3 = rt[row];
      #pragma unroll
      for (int nt = 0; nt < 4; ++nt) {
        float v = acc[mtl][nt][r]
                + p0 * wn4[nt][0] + p1 * wn4[nt][1] + p2 * wn4[nt][2] + p3 * wn4[nt][3];
        msgs[row][nt * 16 + fr] = (row == LQ - 1) ? (unsigned short)0 : f2bf(v);
      }
    }
  }
  __syncthreads();   // b3: msgs + selidx ready

  // ================= phase E: gather + epilogue =================
  #pragma unroll
  for (int ntl = 0; ntl < 2; ++ntl) {
    int col = (ntb + ntl) * 16 + fr;
    float ws0 = W_self[64 * DOUT + col], ws1 = W_self[65 * DOUT + col];
    float ws2 = W_self[66 * DOUT + col], ws3 = W_self[67 * DOUT + col];
    float bi = bias[col];
    #pragma unroll
    for (int r = 0; r < 4; ++r) {
      int q = mt * 16 + fg * 4 + r;
      int row = T0C + q;
      uint4 sv = selidx[q];
      float agg = 0.f;
      #pragma unroll
      for (int s = 0; s < KK; ++s) {
        uint32_t wd = (s < 4) ? sv.x : (s < 8) ? sv.y : (s < 12) ? sv.z : sv.w;
        int j = (wd >> ((s & 3) * 8)) & 0xff;
        unsigned short mv = msgs[j][col];
        agg += __uint_as_float((uint32_t)mv << 16);
      }
      float v = acc2[ntl][r] + agg + bi
              + px[row] * ws0 + py[row] * ws1 + pz[row] * ws2 + rt[row] * ws3;
      v = fmaxf(v, 0.f);
      outp[((size_t)b * TAU + q) * DOUT + col] = v;
    }
  }
}

extern "C" void kernel_launch(void* const* d_in, const int* in_sizes, int n_in,
                              void* d_out, int out_size, void* d_ws, size_t ws_size,
                              hipStream_t stream) {
  (void)in_sizes; (void)n_in; (void)ws_size; (void)out_size;
  const float* x       = (const float*)d_in[0];
  const float* pos     = (const float*)d_in[1];
  const float* rot     = (const float*)d_in[2];
  const float* old_x   = (const float*)d_in[3];
  const float* old_pos = (const float*)d_in[4];
  const float* old_rot = (const float*)d_in[5];
  const float* W_self  = (const float*)d_in[6];
  const float* W_nbr   = (const float*)d_in[7];
  const float* bias    = (const float*)d_in[8];
  float* out = (float*)d_out;
  unsigned short* wst = (unsigned short*)d_ws;

  hipLaunchKernelGGL(prep_w, dim3(32), dim3(256), 0, stream, W_nbr, W_self, wst);
  hipLaunchKernelGGL(navgcm_fused, dim3(NB), dim3(256), 0, stream,
                     x, pos, rot, old_x, old_pos, old_rot, W_self, W_nbr, bias, wst, out);
}

// Round 9
// 46.417 us; speedup vs baseline: 1.1025x; 1.0743x over previous
//
#include <hip/hip_runtime.h>
#include <hip/hip_bf16.h>
#include <cstdint>
#include <cstddef>

#define NB 2048
#define TAU 32
#define T0C 96
#define LQ 128      // T0 + tau
#define DD 64
#define DOUT 64
#define KK 16

typedef unsigned long long u64;
typedef __attribute__((ext_vector_type(8))) short short8;
typedef __attribute__((ext_vector_type(4))) float f32x4;

#define KINV 1e30   // invalid-key sentinel (valid keys < 2^38)

// exact-rounding helpers: keep d2 bit-identical to the reference (no fma fusion)
__device__ __forceinline__ float fmul_exact(float a, float b) {
  float r; asm("v_mul_f32 %0, %1, %2" : "=v"(r) : "v"(a), "v"(b)); return r;
}
__device__ __forceinline__ float fadd_exact(float a, float b) {
  float r; asm("v_add_f32 %0, %1, %2" : "=v"(r) : "v"(a), "v"(b)); return r;
}
__device__ __forceinline__ unsigned short f2bf(float f) {
  __hip_bfloat16 h = __float2bfloat16(f);
  return *reinterpret_cast<unsigned short*>(&h);
}
__device__ __forceinline__ double shfl_xor_f64(double v, int mask) {
  u64 u = __double_as_longlong(v);
  int lo = __shfl_xor((int)(unsigned)(u & 0xffffffffULL), mask, 64);
  int hi = __shfl_xor((int)(unsigned)(u >> 32), mask, 64);
  return __longlong_as_double(((u64)(unsigned)hi << 32) | (unsigned)lo);
}

// lgkm-only workgroup barrier: does NOT drain vmcnt, so global loads/stores
// stay in flight across it (m201-verified pattern: asm waitcnt + s_barrier).
__device__ __forceinline__ void barrier_lgkm() {
  asm volatile("s_waitcnt lgkmcnt(0)" ::: "memory");
  __builtin_amdgcn_s_barrier();
  __builtin_amdgcn_sched_barrier(0);
}

// compare-exchange: ascending (min to first) / descending (max to first)
#define CA(i, j) { double _lo = fmin(kd[i], kd[j]); double _hi = fmax(kd[i], kd[j]); kd[i] = _lo; kd[j] = _hi; }
#define CD(i, j) { double _lo = fmin(kd[i], kd[j]); double _hi = fmax(kd[i], kd[j]); kd[i] = _hi; kd[j] = _lo; }

// full bitonic sort of kd[0..15], ascending (static network, 80 CAS)
#define SORT16() do { \
  CA(0,1)  CD(2,3)  CA(4,5)  CD(6,7)  CA(8,9)  CD(10,11) CA(12,13) CD(14,15) \
  CA(0,2)  CA(1,3)  CD(4,6)  CD(5,7)  CA(8,10) CA(9,11)  CD(12,14) CD(13,15) \
  CA(0,1)  CA(2,3)  CD(4,5)  CD(6,7)  CA(8,9)  CA(10,11) CD(12,13) CD(14,15) \
  CA(0,4)  CA(1,5)  CA(2,6)  CA(3,7)  CD(8,12) CD(9,13)  CD(10,14) CD(11,15) \
  CA(0,2)  CA(1,3)  CA(4,6)  CA(5,7)  CD(8,10) CD(9,11)  CD(12,14) CD(13,15) \
  CA(0,1)  CA(2,3)  CA(4,5)  CA(6,7)  CD(8,9)  CD(10,11) CD(12,13) CD(14,15) \
  CA(0,8)  CA(1,9)  CA(2,10) CA(3,11) CA(4,12) CA(5,13)  CA(6,14)  CA(7,15)  \
  CA(0,4)  CA(1,5)  CA(2,6)  CA(3,7)  CA(8,12) CA(9,13)  CA(10,14) CA(11,15) \
  CA(0,2)  CA(1,3)  CA(4,6)  CA(5,7)  CA(8,10) CA(9,11)  CA(12,14) CA(13,15) \
  CA(0,1)  CA(2,3)  CA(4,5)  CA(6,7)  CA(8,9)  CA(10,11) CA(12,13) CA(14,15) \
} while (0)

// bitonic merge of a bitonic kd[0..15] -> ascending (4 stages, 32 CAS)
#define MERGE16() do { \
  CA(0,8)  CA(1,9)  CA(2,10) CA(3,11) CA(4,12) CA(5,13)  CA(6,14)  CA(7,15)  \
  CA(0,4)  CA(1,5)  CA(2,6)  CA(3,7)  CA(8,12) CA(9,13)  CA(10,14) CA(11,15) \
  CA(0,2)  CA(1,3)  CA(4,6)  CA(5,7)  CA(8,10) CA(9,11)  CA(12,14) CA(13,15) \
  CA(0,1)  CA(2,3)  CA(4,5)  CA(6,7)  CA(8,9)  CA(10,11) CA(12,13) CA(14,15) \
} while (0)

// merge sorted kd with partner lane's sorted list (xor mask), keep lowest 16
#define SHUF_MERGE(mask) do { \
  double pb[16]; \
  _Pragma("unroll") \
  for (int _i = 0; _i < 16; ++_i) pb[_i] = shfl_xor_f64(kd[15 - _i], mask); \
  _Pragma("unroll") \
  for (int _i = 0; _i < 16; ++_i) kd[_i] = fmin(kd[_i], pb[_i]); \
  MERGE16(); \
} while (0)

// ---------- pre-kernel: bf16 transposed weights into d_ws ----------
__global__ __launch_bounds__(256) void prep_w(
    const float* __restrict__ W_nbr, const float* __restrict__ W_self,
    unsigned short* __restrict__ wst) {
  int idx = blockIdx.x * 256 + threadIdx.x;   // grid 32 -> 8192
  int m = idx & 4095;
  int n = m >> 6, k = m & 63;
  const float* src = (idx < 4096) ? W_nbr : W_self;
  wst[idx] = f2bf(src[k * DOUT + n]);
}

__global__ __launch_bounds__(256, 4) void navgcm_fused(
    const float* __restrict__ x, const float* __restrict__ pos_in, const float* __restrict__ rot_in,
    const float* __restrict__ old_x, const float* __restrict__ old_pos, const float* __restrict__ old_rot,
    const float* __restrict__ W_self, const float* __restrict__ W_nbr, const float* __restrict__ bias,
    const unsigned short* __restrict__ wst,
    float* __restrict__ outp)
{
  const int b = blockIdx.x;
  const int tid = threadIdx.x;
  const int lane = tid & 63;
  const int wv = tid >> 6;
  const int fr = lane & 15;   // MFMA fragment row/col within tile
  const int fg = lane >> 4;   // MFMA fragment k-group / row-group

  // union: Hs[128][72] ushort (18432 B, staged after selection) <-> msgs bf16 [128][68]
  __shared__ __align__(16) unsigned char uni[18432];
  __shared__ float px[LQ], py[LQ], pz[LQ], rt[LQ];
  __shared__ uint4 selidx[32];

  unsigned short (*Hs)[72] = reinterpret_cast<unsigned short(*)[72]>(uni);
  unsigned short (*msgs)[68] = reinterpret_cast<unsigned short(*)[68]>(uni);

  // ====== phase A0: issue pos loads (first), then H loads — no waits ======
  const bool haspos = tid < LQ;
  float p0 = 0.f, p1 = 0.f, p2 = 0.f, rr = 0.f;
  if (haspos) {
    int t = tid;
    if (t < T0C) {
      const float* s = old_pos + ((size_t)b * LQ + t) * 3;
      p0 = s[0]; p1 = s[1]; p2 = s[2];
      rr = old_rot[(size_t)b * LQ + t];
    } else {
      const float* s = pos_in + ((size_t)b * TAU + (t - T0C)) * 3;
      p0 = s[0]; p1 = s[1]; p2 = s[2];
      rr = rot_in[(size_t)b * TAU + (t - T0C)];
    }
  }

  float4 v[8];
  #pragma unroll
  for (int it = 0; it < 8; ++it) {
    int n = tid + 256 * it;              // [0,2048): row = n>>4, c4 = n&15
    int row = n >> 4, c4 = n & 15;
    const float4* src = (row < T0C)
        ? (const float4*)(old_x + ((size_t)b * LQ + row) * DD)
        : (const float4*)(x + ((size_t)b * TAU + (row - T0C)) * DD);
    v[it] = src[c4];
  }

  // stage pos to LDS + emit new_pos/new_rot (stores drain at kernel end)
  float* dpos = outp + (size_t)NB * TAU * DOUT + (size_t)NB * LQ * DD;
  float* drot = dpos + (size_t)NB * LQ * 3;
  if (haspos) {
    px[tid] = p0; py[tid] = p1; pz[tid] = p2; rt[tid] = rr;
    size_t g = (size_t)b * LQ + tid;
    dpos[g * 3 + 0] = p0; dpos[g * 3 + 1] = p1; dpos[g * 3 + 2] = p2;
    drot[g] = rr;
  }
  barrier_lgkm();   // b0: pos ready; H loads remain in flight

  // ========== phase B: selection (hides H-load latency) ==========
  {
    const int q = tid >> 3, s8 = tid & 7;
    const int i = T0C + q;
    const float pix = px[i], piy = py[i], piz = pz[i];
    double kd[16];
    #pragma unroll
    for (int c = 0; c < 16; ++c) {
      int j = 8 * c + s8;
      float dx = pix - px[j], dy = piy - py[j], dz = piz - pz[j];
      float d2 = fadd_exact(fadd_exact(fmul_exact(dx, dx), fmul_exact(dy, dy)),
                            fmul_exact(dz, dz));
      bool valid = (d2 <= 1.0f) && (j < i);
      double key = fma((double)__float_as_uint(d2), 128.0, (double)j);
      kd[c] = valid ? key : KINV;
    }
    SORT16();          // ascending per-thread sublist
    SHUF_MERGE(1);     // 8 -> 4 lists
    SHUF_MERGE(2);     // 4 -> 2
    SHUF_MERGE(4);     // 2 -> 1

    if (s8 == 0) {
      uint32_t w[4] = {0u, 0u, 0u, 0u};
      #pragma unroll
      for (int t = 0; t < KK; ++t) {
        double kv = kd[t];
        uint32_t jj;
        if (kv >= 1e29) {
          jj = 127u;                         // sentinel -> zero msg row
        } else {
          uint32_t d2b = (uint32_t)(kv * 0.0078125);       // trunc(kv/128)
          double rem = kv - 128.0 * (double)d2b;           // exact
          jj = (uint32_t)rem;
        }
        w[t >> 2] |= jj << ((t & 3) * 8);
      }
      uint4 sv; sv.x = w[0]; sv.y = w[1]; sv.z = w[2]; sv.w = w[3];
      selidx[q] = sv;
    }
  }

  // ====== phase A1: Hs to LDS + new_x stores (loads have landed by now) ======
  float4* dnx = (float4*)(outp + (size_t)NB * TAU * DOUT);
  #pragma unroll
  for (int it = 0; it < 8; ++it) {
    int n = tid + 256 * it;
    int row = n >> 4, c4 = n & 15;
    ushort4 w4;
    w4.x = f2bf(v[it].x); w4.y = f2bf(v[it].y); w4.z = f2bf(v[it].z); w4.w = f2bf(v[it].w);
    *reinterpret_cast<ushort4*>(&Hs[row][c4 * 4]) = w4;
    dnx[(size_t)b * 2048 + n] = v[it];
  }
  barrier_lgkm();   // b1: Hs + selidx ready (stores NOT drained)

  // ================= phase C: MFMA (B-frags direct from d_ws) =================
  const unsigned short* wn_t = wst;            // [64][64] bf16, [n][k]
  const unsigned short* ws_t = wst + 4096;

  short8 bW[4][2];
  #pragma unroll
  for (int nt = 0; nt < 4; ++nt)
    #pragma unroll
    for (int ks = 0; ks < 2; ++ks)
      bW[nt][ks] = *reinterpret_cast<const short8*>(&wn_t[(nt * 16 + fr) * 64 + ks * 32 + fg * 8]);

  f32x4 acc[2][4];
  #pragma unroll
  for (int m = 0; m < 2; ++m)
    #pragma unroll
    for (int n = 0; n < 4; ++n)
      acc[m][n] = (f32x4){0.f, 0.f, 0.f, 0.f};

  #pragma unroll
  for (int mtl = 0; mtl < 2; ++mtl) {
    int mrow = (2 * wv + mtl) * 16;
    short8 a0 = *reinterpret_cast<const short8*>(&Hs[mrow + fr][fg * 8]);
    short8 a1 = *reinterpret_cast<const short8*>(&Hs[mrow + fr][32 + fg * 8]);
    #pragma unroll
    for (int nt = 0; nt < 4; ++nt) {
      acc[mtl][nt] = __builtin_amdgcn_mfma_f32_16x16x32_bf16(a0, bW[nt][0], acc[mtl][nt], 0, 0, 0);
      acc[mtl][nt] = __builtin_amdgcn_mfma_f32_16x16x32_bf16(a1, bW[nt][1], acc[mtl][nt], 0, 0, 0);
    }
  }

  // self-term MFMA (registers only)
  const int mt = wv & 1;
  const int ntb = (wv >> 1) * 2;
  short8 aQ0 = *reinterpret_cast<const short8*>(&Hs[T0C + mt * 16 + fr][fg * 8]);
  short8 aQ1 = *reinterpret_cast<const short8*>(&Hs[T0C + mt * 16 + fr][32 + fg * 8]);
  f32x4 acc2[2];
  #pragma unroll
  for (int n = 0; n < 2; ++n) acc2[n] = (f32x4){0.f, 0.f, 0.f, 0.f};
  #pragma unroll
  for (int ntl = 0; ntl < 2; ++ntl) {
    int nt = ntb + ntl;
    short8 b0 = *reinterpret_cast<const short8*>(&ws_t[(nt * 16 + fr) * 64 + fg * 8]);
    short8 b1 = *reinterpret_cast<const short8*>(&ws_t[(nt * 16 + fr) * 64 + 32 + fg * 8]);
    acc2[ntl] = __builtin_amdgcn_mfma_f32_16x16x32_bf16(aQ0, b0, acc2[ntl], 0, 0, 0);
    acc2[ntl] = __builtin_amdgcn_mfma_f32_16x16x32_bf16(aQ1, b1, acc2[ntl], 0, 0, 0);
  }
  barrier_lgkm();   // b2: all Hs reads done -> union reusable as msgs

  // ================= phase D: msgs = bf16(acc + pos-terms) -> LDS =================
  float wn4[4][4];
  #pragma unroll
  for (int nt = 0; nt < 4; ++nt) {
    int col = nt * 16 + fr;
    wn4[nt][0] = W_nbr[64 * DOUT + col];
    wn4[nt][1] = W_nbr[65 * DOUT + col];
    wn4[nt][2] = W_nbr[66 * DOUT + col];
    wn4[nt][3] = W_nbr[67 * DOUT + col];
  }
  #pragma unroll
  for (int mtl = 0; mtl < 2; ++mtl) {
    #pragma unroll
    for (int r = 0; r < 4; ++r) {
      int row = (2 * wv + mtl) * 16 + fg * 4 + r;   // C/D: row=(lane>>4)*4+reg
      float q0 = px[row], q1 = py[row], q2 = pz[row], q3 = rt[row];
      #pragma unroll
      for (int nt = 0; nt < 4; ++nt) {
        float vv = acc[mtl][nt][r]
                 + q0 * wn4[nt][0] + q1 * wn4[nt][1] + q2 * wn4[nt][2] + q3 * wn4[nt][3];
        msgs[row][nt * 16 + fr] = (row == LQ - 1) ? (unsigned short)0 : f2bf(vv);
      }
    }
  }
  barrier_lgkm();   // b3: msgs ready

  // ================= phase E: gather + epilogue =================
  #pragma unroll
  for (int ntl = 0; ntl < 2; ++ntl) {
    int col = (ntb + ntl) * 16 + fr;
    float ws0 = W_self[64 * DOUT + col], ws1 = W_self[65 * DOUT + col];
    float ws2 = W_self[66 * DOUT + col], ws3 = W_self[67 * DOUT + col];
    float bi = bias[col];
    #pragma unroll
    for (int r = 0; r < 4; ++r) {
      int q = mt * 16 + fg * 4 + r;
      int row = T0C + q;
      uint4 sv = selidx[q];
      float agg = 0.f;
      #pragma unroll
      for (int s = 0; s < KK; ++s) {
        uint32_t wd = (s < 4) ? sv.x : (s < 8) ? sv.y : (s < 12) ? sv.z : sv.w;
        int j = (wd >> ((s & 3) * 8)) & 0xff;
        unsigned short mv = msgs[j][col];
        agg += __uint_as_float((uint32_t)mv << 16);
      }
      float vv = acc2[ntl][r] + agg + bi
               + px[row] * ws0 + py[row] * ws1 + pz[row] * ws2 + rt[row] * ws3;
      vv = fmaxf(vv, 0.f);
      outp[((size_t)b * TAU + q) * DOUT + col] = vv;
    }
  }
}

extern "C" void kernel_launch(void* const* d_in, const int* in_sizes, int n_in,
                              void* d_out, int out_size, void* d_ws, size_t ws_size,
                              hipStream_t stream) {
  (void)in_sizes; (void)n_in; (void)ws_size; (void)out_size;
  const float* x       = (const float*)d_in[0];
  const float* pos     = (const float*)d_in[1];
  const float* rot     = (const float*)d_in[2];
  const float* old_x   = (const float*)d_in[3];
  const float* old_pos = (const float*)d_in[4];
  const float* old_rot = (const float*)d_in[5];
  const float* W_self  = (const float*)d_in[6];
  const float* W_nbr   = (const float*)d_in[7];
  const float* bias    = (const float*)d_in[8];
  float* out = (float*)d_out;
  unsigned short* wst = (unsigned short*)d_ws;

  hipLaunchKernelGGL(prep_w, dim3(32), dim3(256), 0, stream, W_nbr, W_self, wst);
  hipLaunchKernelGGL(navgcm_fused, dim3(NB), dim3(256), 0, stream,
                     x, pos, rot, old_x, old_pos, old_rot, W_self, W_nbr, bias, wst, out);
}

// Round 10
// 44.452 us; speedup vs baseline: 1.1513x; 1.0442x over previous
//
#include <hip/hip_runtime.h>
#include <hip/hip_bf16.h>
#include <cstdint>
#include <cstddef>

#define NB 2048
#define TAU 32
#define T0C 96
#define LQ 128      // T0 + tau
#define DD 64
#define DOUT 64
#define KK 16
#define INVK 0xFFFFFFFFu

typedef unsigned long long u64;
typedef unsigned int u32;
typedef __attribute__((ext_vector_type(8))) short short8;
typedef __attribute__((ext_vector_type(4))) float f32x4;

// exact-rounding helpers: keep d2 bit-identical to the reference (no fma fusion)
__device__ __forceinline__ float fmul_exact(float a, float b) {
  float r; asm("v_mul_f32 %0, %1, %2" : "=v"(r) : "v"(a), "v"(b)); return r;
}
__device__ __forceinline__ float fadd_exact(float a, float b) {
  float r; asm("v_add_f32 %0, %1, %2" : "=v"(r) : "v"(a), "v"(b)); return r;
}
__device__ __forceinline__ unsigned short f2bf(float f) {
  __hip_bfloat16 h = __float2bfloat16(f);
  return *reinterpret_cast<unsigned short*>(&h);
}
__device__ __forceinline__ u32 shfl_xor_u32(u32 v, int mask) {
  return (u32)__shfl_xor((int)v, mask, 64);
}

// lgkm-only workgroup barrier: does NOT drain vmcnt (m201-verified pattern)
__device__ __forceinline__ void barrier_lgkm() {
  asm volatile("s_waitcnt lgkmcnt(0)" ::: "memory");
  __builtin_amdgcn_s_barrier();
  __builtin_amdgcn_sched_barrier(0);
}

// u32 compare-exchange: ascending / descending
#define CA(i, j) { u32 _lo = min(kd[i], kd[j]); u32 _hi = max(kd[i], kd[j]); kd[i] = _lo; kd[j] = _hi; }
#define CD(i, j) { u32 _lo = min(kd[i], kd[j]); u32 _hi = max(kd[i], kd[j]); kd[i] = _hi; kd[j] = _lo; }

// full bitonic sort of kd[0..15], ascending (static network, 80 CAS)
#define SORT16() do { \
  CA(0,1)  CD(2,3)  CA(4,5)  CD(6,7)  CA(8,9)  CD(10,11) CA(12,13) CD(14,15) \
  CA(0,2)  CA(1,3)  CD(4,6)  CD(5,7)  CA(8,10) CA(9,11)  CD(12,14) CD(13,15) \
  CA(0,1)  CA(2,3)  CD(4,5)  CD(6,7)  CA(8,9)  CA(10,11) CD(12,13) CD(14,15) \
  CA(0,4)  CA(1,5)  CA(2,6)  CA(3,7)  CD(8,12) CD(9,13)  CD(10,14) CD(11,15) \
  CA(0,2)  CA(1,3)  CA(4,6)  CA(5,7)  CD(8,10) CD(9,11)  CD(12,14) CD(13,15) \
  CA(0,1)  CA(2,3)  CA(4,5)  CA(6,7)  CD(8,9)  CD(10,11) CD(12,13) CD(14,15) \
  CA(0,8)  CA(1,9)  CA(2,10) CA(3,11) CA(4,12) CA(5,13)  CA(6,14)  CA(7,15)  \
  CA(0,4)  CA(1,5)  CA(2,6)  CA(3,7)  CA(8,12) CA(9,13)  CA(10,14) CA(11,15) \
  CA(0,2)  CA(1,3)  CA(4,6)  CA(5,7)  CA(8,10) CA(9,11)  CA(12,14) CA(13,15) \
  CA(0,1)  CA(2,3)  CA(4,5)  CA(6,7)  CA(8,9)  CA(10,11) CA(12,13) CA(14,15) \
} while (0)

// bitonic merge of a bitonic kd[0..15] -> ascending (4 stages, 32 CAS)
#define MERGE16() do { \
  CA(0,8)  CA(1,9)  CA(2,10) CA(3,11) CA(4,12) CA(5,13)  CA(6,14)  CA(7,15)  \
  CA(0,4)  CA(1,5)  CA(2,6)  CA(3,7)  CA(8,12) CA(9,13)  CA(10,14) CA(11,15) \
  CA(0,2)  CA(1,3)  CA(4,6)  CA(5,7)  CA(8,10) CA(9,11)  CA(12,14) CA(13,15) \
  CA(0,1)  CA(2,3)  CA(4,5)  CA(6,7)  CA(8,9)  CA(10,11) CA(12,13) CA(14,15) \
} while (0)

// merge sorted kd with partner lane's sorted list (xor mask), keep lowest 16
#define SHUF_MERGE(mask) do { \
  u32 pb[16]; \
  _Pragma("unroll") \
  for (int _i = 0; _i < 16; ++_i) pb[_i] = shfl_xor_u32(kd[15 - _i], mask); \
  _Pragma("unroll") \
  for (int _i = 0; _i < 16; ++_i) kd[_i] = min(kd[_i], pb[_i]); \
  MERGE16(); \
} while (0)

// ---------- pre-kernel: bf16 transposed weights into d_ws ----------
__global__ __launch_bounds__(256) void prep_w(
    const float* __restrict__ W_nbr, const float* __restrict__ W_self,
    unsigned short* __restrict__ wst) {
  int idx = blockIdx.x * 256 + threadIdx.x;   // grid 32 -> 8192
  int m = idx & 4095;
  int n = m >> 6, k = m & 63;
  const float* src = (idx < 4096) ? W_nbr : W_self;
  wst[idx] = f2bf(src[k * DOUT + n]);
}

__global__ __launch_bounds__(256, 4) void navgcm_fused(
    const float* __restrict__ x, const float* __restrict__ pos_in, const float* __restrict__ rot_in,
    const float* __restrict__ old_x, const float* __restrict__ old_pos, const float* __restrict__ old_rot,
    const float* __restrict__ W_self, const float* __restrict__ W_nbr, const float* __restrict__ bias,
    const unsigned short* __restrict__ wst,
    float* __restrict__ outp)
{
  const int b = blockIdx.x;
  const int tid = threadIdx.x;
  const int lane = tid & 63;
  const int wv = tid >> 6;
  const int fr = lane & 15;   // MFMA fragment row/col within tile
  const int fg = lane >> 4;   // MFMA fragment k-group / row-group

  // union: Hs[128][72] ushort (18432 B) <-> msgs f32 [128][66] (33792 B)
  __shared__ __align__(16) unsigned char uni[33792];
  __shared__ float px[LQ], py[LQ], pz[LQ], rt[LQ];
  __shared__ uint4 selidx[32];

  unsigned short (*Hs)[72] = reinterpret_cast<unsigned short(*)[72]>(uni);
  float (*msgs)[66] = reinterpret_cast<float(*)[66]>(uni);

  // ====== phase A0: issue pos loads (first), then H loads — no waits ======
  const bool haspos = tid < LQ;
  float p0 = 0.f, p1 = 0.f, p2 = 0.f, rr = 0.f;
  if (haspos) {
    int t = tid;
    if (t < T0C) {
      const float* s = old_pos + ((size_t)b * LQ + t) * 3;
      p0 = s[0]; p1 = s[1]; p2 = s[2];
      rr = old_rot[(size_t)b * LQ + t];
    } else {
      const float* s = pos_in + ((size_t)b * TAU + (t - T0C)) * 3;
      p0 = s[0]; p1 = s[1]; p2 = s[2];
      rr = rot_in[(size_t)b * TAU + (t - T0C)];
    }
  }

  float4 v[8];
  #pragma unroll
  for (int it = 0; it < 8; ++it) {
    int n = tid + 256 * it;              // [0,2048): row = n>>4, c4 = n&15
    int row = n >> 4, c4 = n & 15;
    const float4* src = (row < T0C)
        ? (const float4*)(old_x + ((size_t)b * LQ + row) * DD)
        : (const float4*)(x + ((size_t)b * TAU + (row - T0C)) * DD);
    v[it] = src[c4];
  }

  // stage pos to LDS + emit new_pos/new_rot (stores drain at kernel end)
  float* dpos = outp + (size_t)NB * TAU * DOUT + (size_t)NB * LQ * DD;
  float* drot = dpos + (size_t)NB * LQ * 3;
  if (haspos) {
    px[tid] = p0; py[tid] = p1; pz[tid] = p2; rt[tid] = rr;
    size_t g = (size_t)b * LQ + tid;
    dpos[g * 3 + 0] = p0; dpos[g * 3 + 1] = p1; dpos[g * 3 + 2] = p2;
    drot[g] = rr;
  }
  barrier_lgkm();   // b0: pos ready; H loads remain in flight

  // ========== phase B: u32 top-16-set selection (hides H-load latency) ==========
  {
    const int q = tid >> 3, s8 = tid & 7;
    const int i = T0C + q;
    const float pix = px[i], piy = py[i], piz = pz[i];

    // original per-candidate keys (d2 bits; INVK if invalid). j = 8c + s8.
    u32 kb[16];
    #pragma unroll
    for (int c = 0; c < 16; ++c) {
      int j = 8 * c + s8;
      float dx = pix - px[j], dy = piy - py[j], dz = piz - pz[j];
      float d2 = fadd_exact(fadd_exact(fmul_exact(dx, dx), fmul_exact(dy, dy)),
                            fmul_exact(dz, dz));
      bool valid = (d2 <= 1.0f) && (j < i);
      kb[c] = valid ? __float_as_uint(d2) : INVK;
    }

    // sorted working copy + 3-level min-merge across the 8 lanes of this query
    u32 kd[16];
    #pragma unroll
    for (int c = 0; c < 16; ++c) kd[c] = kb[c];
    SORT16();
    SHUF_MERGE(1);
    SHUF_MERGE(2);
    SHUF_MERGE(4);   // all 8 lanes now hold the global sorted top-16 d2bits

    const u32 T = kd[15];
    int nless = 0;
    #pragma unroll
    for (int t = 0; t < KK; ++t) nless += (kd[t] < T) ? 1 : 0;
    const int needT = (T == INVK) ? 0 : (KK - nless);

    // selection mask over own candidates: all < T
    u32 selmask = 0;
    #pragma unroll
    for (int c = 0; c < 16; ++c) selmask |= (kb[c] < T) ? (1u << c) : 0u;

    // ties at T: pick the needT smallest j (ascending j == lax.top_k stable rule)
    u32 em = 0;
    #pragma unroll
    for (int c = 0; c < 16; ++c) em |= (kb[c] == T) ? (1u << c) : 0u;
    if (T == INVK) em = 0;
    for (int t = 0; __any(t < needT); ++t) {
      bool act = t < needT;
      u32 myj = (act && em) ? (u32)(8 * __builtin_ctz(em) + s8) : 0xFFFFu;
      u32 gj = myj;
      gj = min(gj, shfl_xor_u32(gj, 1));
      gj = min(gj, shfl_xor_u32(gj, 2));
      gj = min(gj, shfl_xor_u32(gj, 4));
      if (act && myj == gj && myj != 0xFFFFu) {
        int c = __builtin_ctz(em);
        selmask |= 1u << c;
        em &= em - 1;
      }
    }

    // compact selected j's into selidx[q] (byte list; pad = 127 -> zero msg row)
    if (s8 < 4) ((u32*)selidx)[q * 4 + s8] = 0x7F7F7F7Fu;
    int cnt = __builtin_popcount(selmask);
    int pre = 0;
    #pragma unroll
    for (int k = 0; k < 7; ++k) {
      int vt = __shfl(cnt, (lane & ~7) + k, 64);
      pre += (k < s8) ? vt : 0;
    }
    unsigned char* sp = (unsigned char*)selidx + q * 16 + pre;
    u32 m = selmask;
    while (m) {
      int c = __builtin_ctz(m);
      m &= m - 1;
      *sp++ = (unsigned char)(8 * c + s8);
    }
  }

  // ====== phase A1: Hs to LDS + new_x stores (loads have landed by now) ======
  float4* dnx = (float4*)(outp + (size_t)NB * TAU * DOUT);
  #pragma unroll
  for (int it = 0; it < 8; ++it) {
    int n = tid + 256 * it;
    int row = n >> 4, c4 = n & 15;
    ushort4 w4;
    w4.x = f2bf(v[it].x); w4.y = f2bf(v[it].y); w4.z = f2bf(v[it].z); w4.w = f2bf(v[it].w);
    *reinterpret_cast<ushort4*>(&Hs[row][c4 * 4]) = w4;
    dnx[(size_t)b * 2048 + n] = v[it];
  }
  barrier_lgkm();   // b1: Hs + selidx ready (stores NOT drained)

  // ================= phase C: MFMA (B-frags direct from d_ws) =================
  const unsigned short* wn_t = wst;            // [64][64] bf16, [n][k]
  const unsigned short* ws_t = wst + 4096;

  short8 bW[4][2];
  #pragma unroll
  for (int nt = 0; nt < 4; ++nt)
    #pragma unroll
    for (int ks = 0; ks < 2; ++ks)
      bW[nt][ks] = *reinterpret_cast<const short8*>(&wn_t[(nt * 16 + fr) * 64 + ks * 32 + fg * 8]);

  f32x4 acc[2][4];
  #pragma unroll
  for (int m = 0; m < 2; ++m)
    #pragma unroll
    for (int n = 0; n < 4; ++n)
      acc[m][n] = (f32x4){0.f, 0.f, 0.f, 0.f};

  #pragma unroll
  for (int mtl = 0; mtl < 2; ++mtl) {
    int mrow = (2 * wv + mtl) * 16;
    short8 a0 = *reinterpret_cast<const short8*>(&Hs[mrow + fr][fg * 8]);
    short8 a1 = *reinterpret_cast<const short8*>(&Hs[mrow + fr][32 + fg * 8]);
    #pragma unroll
    for (int nt = 0; nt < 4; ++nt) {
      acc[mtl][nt] = __builtin_amdgcn_mfma_f32_16x16x32_bf16(a0, bW[nt][0], acc[mtl][nt], 0, 0, 0);
      acc[mtl][nt] = __builtin_amdgcn_mfma_f32_16x16x32_bf16(a1, bW[nt][1], acc[mtl][nt], 0, 0, 0);
    }
  }

  // self-term MFMA (registers only)
  const int mt = wv & 1;
  const int ntb = (wv >> 1) * 2;
  short8 aQ0 = *reinterpret_cast<const short8*>(&Hs[T0C + mt * 16 + fr][fg * 8]);
  short8 aQ1 = *reinterpret_cast<const short8*>(&Hs[T0C + mt * 16 + fr][32 + fg * 8]);
  f32x4 acc2[2];
  #pragma unroll
  for (int n = 0; n < 2; ++n) acc2[n] = (f32x4){0.f, 0.f, 0.f, 0.f};
  #pragma unroll
  for (int ntl = 0; ntl < 2; ++ntl) {
    int nt = ntb + ntl;
    short8 b0 = *reinterpret_cast<const short8*>(&ws_t[(nt * 16 + fr) * 64 + fg * 8]);
    short8 b1 = *reinterpret_cast<const short8*>(&ws_t[(nt * 16 + fr) * 64 + 32 + fg * 8]);
    acc2[ntl] = __builtin_amdgcn_mfma_f32_16x16x32_bf16(aQ0, b0, acc2[ntl], 0, 0, 0);
    acc2[ntl] = __builtin_amdgcn_mfma_f32_16x16x32_bf16(aQ1, b1, acc2[ntl], 0, 0, 0);
  }
  barrier_lgkm();   // b2: all Hs reads done -> union reusable as msgs

  // ================= phase D: msgs = acc + pos-terms -> LDS (f32) =================
  float wn4[4][4];
  #pragma unroll
  for (int nt = 0; nt < 4; ++nt) {
    int col = nt * 16 + fr;
    wn4[nt][0] = W_nbr[64 * DOUT + col];
    wn4[nt][1] = W_nbr[65 * DOUT + col];
    wn4[nt][2] = W_nbr[66 * DOUT + col];
    wn4[nt][3] = W_nbr[67 * DOUT + col];
  }
  #pragma unroll
  for (int mtl = 0; mtl < 2; ++mtl) {
    #pragma unroll
    for (int r = 0; r < 4; ++r) {
      int row = (2 * wv + mtl) * 16 + fg * 4 + r;   // C/D: row=(lane>>4)*4+reg
      float q0 = px[row], q1 = py[row], q2 = pz[row], q3 = rt[row];
      #pragma unroll
      for (int nt = 0; nt < 4; ++nt) {
        float vv = acc[mtl][nt][r]
                 + q0 * wn4[nt][0] + q1 * wn4[nt][1] + q2 * wn4[nt][2] + q3 * wn4[nt][3];
        msgs[row][nt * 16 + fr] = (row == LQ - 1) ? 0.f : vv;  // row 127 = sentinel sink
      }
    }
  }
  barrier_lgkm();   // b3: msgs ready

  // ================= phase E: gather + epilogue =================
  #pragma unroll
  for (int ntl = 0; ntl < 2; ++ntl) {
    int col = (ntb + ntl) * 16 + fr;
    float ws0 = W_self[64 * DOUT + col], ws1 = W_self[65 * DOUT + col];
    float ws2 = W_self[66 * DOUT + col], ws3 = W_self[67 * DOUT + col];
    float bi = bias[col];
    #pragma unroll
    for (int r = 0; r < 4; ++r) {
      int q = mt * 16 + fg * 4 + r;
      int row = T0C + q;
      uint4 sv = selidx[q];
      float agg = 0.f;
      #pragma unroll
      for (int s = 0; s < KK; ++s) {
        u32 wd = (s < 4) ? sv.x : (s < 8) ? sv.y : (s < 12) ? sv.z : sv.w;
        int j = (wd >> ((s & 3) * 8)) & 0xff;
        agg += msgs[j][col];
      }
      float vv = acc2[ntl][r] + agg + bi
               + px[row] * ws0 + py[row] * ws1 + pz[row] * ws2 + rt[row] * ws3;
      vv = fmaxf(vv, 0.f);
      outp[((size_t)b * TAU + q) * DOUT + col] = vv;
    }
  }
}

extern "C" void kernel_launch(void* const* d_in, const int* in_sizes, int n_in,
                              void* d_out, int out_size, void* d_ws, size_t ws_size,
                              hipStream_t stream) {
  (void)in_sizes; (void)n_in; (void)ws_size; (void)out_size;
  const float* x       = (const float*)d_in[0];
  const float* pos     = (const float*)d_in[1];
  const float* rot     = (const float*)d_in[2];
  const float* old_x   = (const float*)d_in[3];
  const float* old_pos = (const float*)d_in[4];
  const float* old_rot = (const float*)d_in[5];
  const float* W_self  = (const float*)d_in[6];
  const float* W_nbr   = (const float*)d_in[7];
  const float* bias    = (const float*)d_in[8];
  float* out = (float*)d_out;
  unsigned short* wst = (unsigned short*)d_ws;

  hipLaunchKernelGGL(prep_w, dim3(32), dim3(256), 0, stream, W_nbr, W_self, wst);
  hipLaunchKernelGGL(navgcm_fused, dim3(NB), dim3(256), 0, stream,
                     x, pos, rot, old_x, old_pos, old_rot, W_self, W_nbr, bias, wst, out);
}